// Round 10
// baseline (49.038 us; speedup 1.0000x reference)
//
#include <hip/hip_runtime.h>

#define NN 20000
#define VV 100000
#define CC 5000
#define MM 32
#define KK 2048
#define DD 128

// ws: active[CC] @0 ; w1t bf16 @32768 (96KB) ; w3t bf16 @131072 (16KB)
#define WS_W1T  32768
#define WS_W3T  131072

typedef __attribute__((ext_vector_type(8))) short bf16x8;
typedef __attribute__((ext_vector_type(4))) float f32x4;

__device__ __forceinline__ unsigned f2bf_rne(float f) {  // bf16 in low 16 bits
  unsigned u = __builtin_bit_cast(unsigned, f);
  u += 0x7fffu + ((u >> 16) & 1u);
  return u >> 16;
}
__device__ __forceinline__ float bf2f(unsigned h) {
  unsigned u = h << 16;
  return __builtin_bit_cast(float, u);
}

// ---------------- K0: init = zero+scatter (block 0) | W1->bf16^T | W3->bf16^T ----------------
__global__ __launch_bounds__(256) void init_k(const int* __restrict__ cidx,
    int* __restrict__ active, const float* __restrict__ W1,
    unsigned short* __restrict__ w1t, const float* __restrict__ W3,
    unsigned short* __restrict__ w3t) {
  int b = blockIdx.x, tid = threadIdx.x;
  if (b == 0) {
    for (int i = tid; i < CC; i += 256) active[i] = 0;
    __syncthreads();
    for (int k = tid; k < KK; k += 256) active[cidx[k]] = 1;
  } else if (b <= 192) {
    int i = (b - 1) * 256 + tid;        // w1t[c][k], c<128, k<384
    int c = i / 384, k = i % 384;
    w1t[i] = (unsigned short)f2bf_rne(W1[(size_t)k * DD + c]);
  } else {                               // b == 193 ; w3t[h][k], h<64, k<128
    for (int i = tid; i < 64 * DD; i += 256) {
      int h = i >> 7, k = i & 127;
      w3t[i] = (unsigned short)f2bf_rne(W3[(size_t)k * 64 + h]);
    }
  }
}

// ---------------- K1: main = feat stage (+inline member emb) + pred1/pred2 MFMA + select --------
// 512 thr, 32 nodes/block, 625 blocks. LDS = feat hi/lo only (~50 KB -> 2 blocks/CU).
// Member embedding computed inline per use-row (wave-pair, shfl-broadcast meta).
// B-fragments (w1t, w3t bf16) read directly from global (L2-resident).
// Wave w: rt=w&1 -> rows rt*16..+15; ch=w>>1 -> pred1 cols ch*32..+31 / pred2 hidden ch*16..+15.
// C/D mapping (verified R6): out_row = rt*16 + (lane>>4)*4 + j, col = tile_base + (lane&15).
__global__ __launch_bounds__(512) void main_k(const float* __restrict__ node_emb,
    const float* __restrict__ cemb,
    const unsigned short* __restrict__ w1t, const float* __restrict__ b1,
    const float* __restrict__ W2, const float* __restrict__ b2v,
    const unsigned short* __restrict__ w3t, const float* __restrict__ b3,
    const float* __restrict__ W4, const float* __restrict__ b4v,
    const int* __restrict__ n2c, const int* __restrict__ c2n,
    const int* __restrict__ mnum, const float* __restrict__ mscore,
    const int* __restrict__ active, const int* __restrict__ nodes,
    float* __restrict__ out) {
  __shared__ __align__(16) unsigned short s_hi[32][392];   // 24.5 KB
  __shared__ __align__(16) unsigned short s_lo[32][392];   // 24.5 KB
  __shared__ int s_v[32], s_cm[32], s_use[32];
  __shared__ float s_r1[32][4], s_r2[32][4];
  int tid = threadIdx.x;
  int n0 = blockIdx.x * 32;
  if (tid < 32) {
    int v = nodes[n0 + tid], cm = n2c[v];
    s_v[tid] = v; s_cm[tid] = cm; s_use[tid] = active[cm];
  }
  __syncthreads();
  {  // phase 1: cols 0..255 (node_emb | cemb), 32 rows x 64 float4
    #pragma unroll
    for (int it = 0; it < 4; ++it) {
      int i4 = it * 512 + tid;
      int row = i4 >> 6, pos = i4 & 63;
      int off = pos * 4;
      int use = s_use[row];
      float4 f;
      if (off < DD)
        f = *(const float4*)(node_emb + (size_t)(n0 + row) * DD + off);
      else
        f = use ? *(const float4*)(cemb + (size_t)s_v[row] * DD + (off - DD))
                : make_float4(0.f, 0.f, 0.f, 0.f);
      unsigned h0 = f2bf_rne(f.x), h1 = f2bf_rne(f.y),
               h2 = f2bf_rne(f.z), h3 = f2bf_rne(f.w);
      unsigned l0 = f2bf_rne(f.x - bf2f(h0)), l1 = f2bf_rne(f.y - bf2f(h1)),
               l2 = f2bf_rne(f.z - bf2f(h2)), l3 = f2bf_rne(f.w - bf2f(h3));
      *(uint2*)&s_hi[row][off] = make_uint2(h0 | (h1 << 16), h2 | (h3 << 16));
      *(uint2*)&s_lo[row][off] = make_uint2(l0 | (l1 << 16), l2 | (l3 << 16));
    }
  }
  {  // phase 2: member embedding inline -> cols 256..383; wave-pair per row
    int lane = tid & 63;
    int d = tid & 127;        // dim within the pair
    int pair = tid >> 7;      // 0..3
    for (int r = pair; r < 32; r += 4) {
      float acc = 0.f;
      if (s_use[r]) {          // wave-uniform
        int cm = s_cm[r];
        float sc = 0.f; int nc = 0;
        if (lane < 32) {
          int mem = c2n[cm * MM + lane];
          nc = n2c[mem];
          bool valid = (lane < mnum[cm]) && (active[nc] != 0);
          sc = valid ? mscore[cm * MM + lane] : 0.f;
        }
        #pragma unroll
        for (int m = 0; m < MM; ++m) {
          float s = __shfl(sc, m, 64);
          int ncm = __shfl(nc, m, 64);
          acc = fmaf(s, cemb[(size_t)ncm * DD + d], acc);
        }
      }
      unsigned h = f2bf_rne(acc);
      unsigned l = f2bf_rne(acc - bf2f(h));
      s_hi[r][2 * DD + d] = (unsigned short)h;
      s_lo[r][2 * DD + d] = (unsigned short)l;
    }
  }
  __syncthreads();
  int lane = tid & 63, w = tid >> 6;
  int rt = w & 1, ch = w >> 1;
  int lrow = lane & 15, lkq = lane >> 4, lkb = lkq * 8;
  const char* ah = (const char*)&s_hi[rt * 16 + lrow][0] + lkb * 2;
  const char* al = (const char*)&s_lo[rt * 16 + lrow][0] + lkb * 2;
  const unsigned short* bp0 = w1t + (size_t)(ch * 32 + lrow) * 384 + lkb;
  const unsigned short* bp1 = bp0 + 16 * 384;
  const unsigned short* w3p = w3t + (size_t)(ch * 16 + lrow) * DD + lkb;
  f32x4 acc0 = {0.f, 0.f, 0.f, 0.f}, acc1 = {0.f, 0.f, 0.f, 0.f};
  f32x4 p2   = {0.f, 0.f, 0.f, 0.f};
  #pragma unroll
  for (int k0 = 0; k0 < DD; k0 += 32) {  // pred1 + pred2 share A-frags
    bf16x8 vah = *(const bf16x8*)(ah + k0 * 2);
    bf16x8 val = *(const bf16x8*)(al + k0 * 2);
    bf16x8 vb0 = *(const bf16x8*)(bp0 + k0);
    bf16x8 vb1 = *(const bf16x8*)(bp1 + k0);
    bf16x8 vb2 = *(const bf16x8*)(w3p + k0);
    acc0 = __builtin_amdgcn_mfma_f32_16x16x32_bf16(vah, vb0, acc0, 0, 0, 0);
    acc0 = __builtin_amdgcn_mfma_f32_16x16x32_bf16(val, vb0, acc0, 0, 0, 0);
    acc1 = __builtin_amdgcn_mfma_f32_16x16x32_bf16(vah, vb1, acc1, 0, 0, 0);
    acc1 = __builtin_amdgcn_mfma_f32_16x16x32_bf16(val, vb1, acc1, 0, 0, 0);
    p2   = __builtin_amdgcn_mfma_f32_16x16x32_bf16(vah, vb2, p2, 0, 0, 0);
    p2   = __builtin_amdgcn_mfma_f32_16x16x32_bf16(val, vb2, p2, 0, 0, 0);
  }
  #pragma unroll
  for (int k0 = DD; k0 < 3 * DD; k0 += 32) {  // pred1 only
    bf16x8 vah = *(const bf16x8*)(ah + k0 * 2);
    bf16x8 val = *(const bf16x8*)(al + k0 * 2);
    bf16x8 vb0 = *(const bf16x8*)(bp0 + k0);
    bf16x8 vb1 = *(const bf16x8*)(bp1 + k0);
    acc0 = __builtin_amdgcn_mfma_f32_16x16x32_bf16(vah, vb0, acc0, 0, 0, 0);
    acc0 = __builtin_amdgcn_mfma_f32_16x16x32_bf16(val, vb0, acc0, 0, 0, 0);
    acc1 = __builtin_amdgcn_mfma_f32_16x16x32_bf16(vah, vb1, acc1, 0, 0, 0);
    acc1 = __builtin_amdgcn_mfma_f32_16x16x32_bf16(val, vb1, acc1, 0, 0, 0);
  }
  {  // pred1 epilogue
    int c0 = ch * 32 + lrow, c1 = c0 + 16;
    float b1a = b1[c0], b1b = b1[c1];
    float w2a = W2[c0], w2b = W2[c1];
    float vsum[4];
    #pragma unroll
    for (int j = 0; j < 4; ++j)
      vsum[j] = fmaxf(acc0[j] + b1a, 0.f) * w2a + fmaxf(acc1[j] + b1b, 0.f) * w2b;
    #pragma unroll
    for (int m = 1; m <= 8; m <<= 1)
      #pragma unroll
      for (int j = 0; j < 4; ++j) vsum[j] += __shfl_xor(vsum[j], m, 64);
    if (lrow == 0) {
      #pragma unroll
      for (int j = 0; j < 4; ++j) s_r1[rt * 16 + lkq * 4 + j][ch] = vsum[j];
    }
  }
  {  // pred2 epilogue
    int h = ch * 16 + lrow;
    float b3v = b3[h], w4v = W4[h];
    float q[4];
    #pragma unroll
    for (int j = 0; j < 4; ++j) q[j] = fmaxf(p2[j] + b3v, 0.f) * w4v;
    #pragma unroll
    for (int m = 1; m <= 8; m <<= 1)
      #pragma unroll
      for (int j = 0; j < 4; ++j) q[j] += __shfl_xor(q[j], m, 64);
    if (lrow == 0) {
      #pragma unroll
      for (int j = 0; j < 4; ++j) s_r2[rt * 16 + lkq * 4 + j][ch] = q[j];
    }
  }
  __syncthreads();
  if (tid < 32) {
    float r;
    if (s_use[tid])
      r = s_r1[tid][0] + s_r1[tid][1] + s_r1[tid][2] + s_r1[tid][3] + b2v[0];
    else
      r = s_r2[tid][0] + s_r2[tid][1] + s_r2[tid][2] + s_r2[tid][3] + b4v[0];
    out[n0 + tid] = r;
  }
}

extern "C" void kernel_launch(void* const* d_in, const int* in_sizes, int n_in,
                              void* d_out, int out_size, void* d_ws, size_t ws_size,
                              hipStream_t stream) {
  const float* node_emb = (const float*)d_in[0];
  const float* mscore   = (const float*)d_in[1];
  const float* cemb     = (const float*)d_in[2];
  const float* W1 = (const float*)d_in[3];
  const float* b1 = (const float*)d_in[4];
  const float* W2 = (const float*)d_in[5];
  const float* b2 = (const float*)d_in[6];
  const float* W3 = (const float*)d_in[7];
  const float* b3 = (const float*)d_in[8];
  const float* W4 = (const float*)d_in[9];
  const float* b4 = (const float*)d_in[10];
  const int* n2c   = (const int*)d_in[11];
  const int* c2n   = (const int*)d_in[12];
  const int* mnum  = (const int*)d_in[13];
  const int* cidx  = (const int*)d_in[14];
  const int* nodes = (const int*)d_in[15];
  float* out = (float*)d_out;

  int* active = (int*)d_ws;
  unsigned short* w1t = (unsigned short*)((char*)d_ws + WS_W1T);
  unsigned short* w3t = (unsigned short*)((char*)d_ws + WS_W3T);

  init_k<<<194, 256, 0, stream>>>(cidx, active, W1, w1t, W3, w3t);
  main_k<<<NN / 32, 512, 0, stream>>>(node_emb, cemb, w1t, b1, W2, b2,
                                      w3t, b3, W4, b4, n2c, c2n, mnum, mscore,
                                      active, nodes, out);
}

// Round 11
// 40.301 us; speedup vs baseline: 1.2168x; 1.2168x over previous
//
#include <hip/hip_runtime.h>

#define NN 20000
#define VV 100000
#define CC 5000
#define MM 32
#define KK 2048
#define DD 128

// ws: active[CC] @0 ; memb @32768 (2.56MB) ; w1t bf16 @2592768 (96KB) ; w3t bf16 @2691072 (16KB)
#define WS_MEMB 32768
#define WS_W1T  2592768
#define WS_W3T  2691072

typedef __attribute__((ext_vector_type(8))) short bf16x8;
typedef __attribute__((ext_vector_type(4))) float f32x4;

__device__ __forceinline__ unsigned f2bf_rne(float f) {  // bf16 in low 16 bits
  unsigned u = __builtin_bit_cast(unsigned, f);
  u += 0x7fffu + ((u >> 16) & 1u);
  return u >> 16;
}
__device__ __forceinline__ float bf2f(unsigned h) {
  unsigned u = h << 16;
  return __builtin_bit_cast(float, u);
}

// ---------------- K0: init = zero+scatter (block 0) | W1->bf16^T | W3->bf16^T ----------------
__global__ __launch_bounds__(256) void init_k(const int* __restrict__ cidx,
    int* __restrict__ active, const float* __restrict__ W1,
    unsigned short* __restrict__ w1t, const float* __restrict__ W3,
    unsigned short* __restrict__ w3t) {
  int b = blockIdx.x, tid = threadIdx.x;
  if (b == 0) {
    for (int i = tid; i < CC; i += 256) active[i] = 0;
    __syncthreads();
    for (int k = tid; k < KK; k += 256) active[cidx[k]] = 1;
  } else if (b <= 192) {
    int i = (b - 1) * 256 + tid;        // w1t[c][k], c<128, k<384
    int c = i / 384, k = i % 384;
    w1t[i] = (unsigned short)f2bf_rne(W1[(size_t)k * DD + c]);
  } else {                               // b == 193 ; w3t[h][k], h<64, k<128
    for (int i = tid; i < 64 * DD; i += 256) {
      int h = i >> 7, k = i & 127;
      w3t[i] = (unsigned short)f2bf_rne(W3[(size_t)k * 64 + h]);
    }
  }
}

// ---------------- K1: member embedding, driven by cidx (2048 blocks) ----------------
// Duplicate cidx entries recompute identical values - deterministic.
__global__ __launch_bounds__(128) void member_emb_k(const int* __restrict__ c2n,
    const int* __restrict__ n2c, const float* __restrict__ mscore,
    const int* __restrict__ mnum, const int* __restrict__ active,
    const int* __restrict__ cidx, const float* __restrict__ cemb,
    float* __restrict__ memb) {
  int c = cidx[blockIdx.x];  // active by construction
  __shared__ float s_sc[MM];
  __shared__ int s_nc[MM];
  int t = threadIdx.x;  // 0..127 = d
  if (t < MM) {
    int mem = c2n[c * MM + t];
    int nc = n2c[mem];
    bool valid = (t < mnum[c]) && (active[nc] != 0);
    s_nc[t] = nc;
    s_sc[t] = valid ? mscore[c * MM + t] : 0.f;
  }
  __syncthreads();
  float acc = 0.f;
  #pragma unroll
  for (int m = 0; m < MM; ++m)  // 32 independent loads in flight
    acc = fmaf(s_sc[m], cemb[(size_t)s_nc[m] * DD + t], acc);
  memb[(size_t)c * DD + t] = acc;
}

// ---------------- K2: main = feat stage + pred1/pred2 MFMA + select ----------------
// 512 thr, 16 rows/block, 1250 blocks. LDS ~26 KB -> 4 blocks/CU (thread-capped), 32 waves/CU.
// B-fragments (w1t, w3t bf16) read directly from global (L2-resident).
// Wave w owns pred1 col-tile w*16..+15; pred2 hidden tile (w&3)*16..+15 (only w<4 writes).
// C/D mapping (verified R6): out_row = (lane>>4)*4 + j, col = tile_base + (lane&15).
__global__ __launch_bounds__(512) void main_k(const float* __restrict__ node_emb,
    const float* __restrict__ cemb, const float* __restrict__ memb,
    const unsigned short* __restrict__ w1t, const float* __restrict__ b1,
    const float* __restrict__ W2, const float* __restrict__ b2v,
    const unsigned short* __restrict__ w3t, const float* __restrict__ b3,
    const float* __restrict__ W4, const float* __restrict__ b4v,
    const int* __restrict__ n2c, const int* __restrict__ active,
    const int* __restrict__ nodes, float* __restrict__ out) {
  __shared__ __align__(16) unsigned short s_hi[16][392];   // 12.25 KB
  __shared__ __align__(16) unsigned short s_lo[16][392];   // 12.25 KB
  __shared__ int s_v[16], s_cm[16], s_use[16];
  __shared__ float s_r1[16][8], s_r2[16][4];
  int tid = threadIdx.x;
  int n0 = blockIdx.x * 16;
  if (tid < 16) {
    int v = nodes[n0 + tid], cm = n2c[v];
    s_v[tid] = v; s_cm[tid] = cm; s_use[tid] = active[cm];
  }
  __syncthreads();
  {  // stage feat hi/lo: 16 rows x 96 float4 = 1536 float4, 3 per thread
    #pragma unroll
    for (int it = 0; it < 3; ++it) {
      int i4 = it * 512 + tid;
      int row = i4 / 96, pos = i4 % 96;
      int off = pos * 4;
      int use = s_use[row];
      float4 f;
      if (off < DD) {
        f = *(const float4*)(node_emb + (size_t)(n0 + row) * DD + off);
      } else if (off < 2 * DD) {
        f = use ? *(const float4*)(cemb + (size_t)s_v[row] * DD + (off - DD))
                : make_float4(0.f, 0.f, 0.f, 0.f);
      } else {
        f = use ? *(const float4*)(memb + (size_t)s_cm[row] * DD + (off - 2 * DD))
                : make_float4(0.f, 0.f, 0.f, 0.f);
      }
      unsigned h0 = f2bf_rne(f.x), h1 = f2bf_rne(f.y),
               h2 = f2bf_rne(f.z), h3 = f2bf_rne(f.w);
      unsigned l0 = f2bf_rne(f.x - bf2f(h0)), l1 = f2bf_rne(f.y - bf2f(h1)),
               l2 = f2bf_rne(f.z - bf2f(h2)), l3 = f2bf_rne(f.w - bf2f(h3));
      *(uint2*)&s_hi[row][off] = make_uint2(h0 | (h1 << 16), h2 | (h3 << 16));
      *(uint2*)&s_lo[row][off] = make_uint2(l0 | (l1 << 16), l2 | (l3 << 16));
    }
  }
  __syncthreads();
  int lane = tid & 63, w = tid >> 6;
  int lrow = lane & 15, lkq = lane >> 4, lkb = lkq * 8;
  const char* ah = (const char*)&s_hi[lrow][0] + lkb * 2;
  const char* al = (const char*)&s_lo[lrow][0] + lkb * 2;
  const unsigned short* bp0 = w1t + (size_t)(w * 16 + lrow) * 384 + lkb;
  const unsigned short* w3p = w3t + (size_t)((w & 3) * 16 + lrow) * DD + lkb;
  f32x4 acc0 = {0.f, 0.f, 0.f, 0.f};
  f32x4 p2   = {0.f, 0.f, 0.f, 0.f};
  #pragma unroll
  for (int k0 = 0; k0 < DD; k0 += 32) {  // pred1 + pred2 share A-frags
    bf16x8 vah = *(const bf16x8*)(ah + k0 * 2);
    bf16x8 val = *(const bf16x8*)(al + k0 * 2);
    bf16x8 vb0 = *(const bf16x8*)(bp0 + k0);
    bf16x8 vb2 = *(const bf16x8*)(w3p + k0);
    acc0 = __builtin_amdgcn_mfma_f32_16x16x32_bf16(vah, vb0, acc0, 0, 0, 0);
    acc0 = __builtin_amdgcn_mfma_f32_16x16x32_bf16(val, vb0, acc0, 0, 0, 0);
    p2   = __builtin_amdgcn_mfma_f32_16x16x32_bf16(vah, vb2, p2, 0, 0, 0);
    p2   = __builtin_amdgcn_mfma_f32_16x16x32_bf16(val, vb2, p2, 0, 0, 0);
  }
  #pragma unroll
  for (int k0 = DD; k0 < 3 * DD; k0 += 32) {  // pred1 only
    bf16x8 vah = *(const bf16x8*)(ah + k0 * 2);
    bf16x8 val = *(const bf16x8*)(al + k0 * 2);
    bf16x8 vb0 = *(const bf16x8*)(bp0 + k0);
    acc0 = __builtin_amdgcn_mfma_f32_16x16x32_bf16(vah, vb0, acc0, 0, 0, 0);
    acc0 = __builtin_amdgcn_mfma_f32_16x16x32_bf16(val, vb0, acc0, 0, 0, 0);
  }
  {  // pred1 epilogue: reduce 16 cols of tile w
    int c0 = w * 16 + lrow;
    float b1a = b1[c0], w2a = W2[c0];
    float vsum[4];
    #pragma unroll
    for (int j = 0; j < 4; ++j) vsum[j] = fmaxf(acc0[j] + b1a, 0.f) * w2a;
    #pragma unroll
    for (int m = 1; m <= 8; m <<= 1)
      #pragma unroll
      for (int j = 0; j < 4; ++j) vsum[j] += __shfl_xor(vsum[j], m, 64);
    if (lrow == 0) {
      #pragma unroll
      for (int j = 0; j < 4; ++j) s_r1[lkq * 4 + j][w] = vsum[j];
    }
  }
  {  // pred2 epilogue (waves 0-3 only write)
    int h = (w & 3) * 16 + lrow;
    float b3v = b3[h], w4v = W4[h];
    float q[4];
    #pragma unroll
    for (int j = 0; j < 4; ++j) q[j] = fmaxf(p2[j] + b3v, 0.f) * w4v;
    #pragma unroll
    for (int m = 1; m <= 8; m <<= 1)
      #pragma unroll
      for (int j = 0; j < 4; ++j) q[j] += __shfl_xor(q[j], m, 64);
    if (lrow == 0 && w < 4) {
      #pragma unroll
      for (int j = 0; j < 4; ++j) s_r2[lkq * 4 + j][w] = q[j];
    }
  }
  __syncthreads();
  if (tid < 16) {
    float r;
    if (s_use[tid]) {
      r = b2v[0];
      #pragma unroll
      for (int c = 0; c < 8; ++c) r += s_r1[tid][c];
    } else {
      r = s_r2[tid][0] + s_r2[tid][1] + s_r2[tid][2] + s_r2[tid][3] + b4v[0];
    }
    out[n0 + tid] = r;
  }
}

extern "C" void kernel_launch(void* const* d_in, const int* in_sizes, int n_in,
                              void* d_out, int out_size, void* d_ws, size_t ws_size,
                              hipStream_t stream) {
  const float* node_emb = (const float*)d_in[0];
  const float* mscore   = (const float*)d_in[1];
  const float* cemb     = (const float*)d_in[2];
  const float* W1 = (const float*)d_in[3];
  const float* b1 = (const float*)d_in[4];
  const float* W2 = (const float*)d_in[5];
  const float* b2 = (const float*)d_in[6];
  const float* W3 = (const float*)d_in[7];
  const float* b3 = (const float*)d_in[8];
  const float* W4 = (const float*)d_in[9];
  const float* b4 = (const float*)d_in[10];
  const int* n2c   = (const int*)d_in[11];
  const int* c2n   = (const int*)d_in[12];
  const int* mnum  = (const int*)d_in[13];
  const int* cidx  = (const int*)d_in[14];
  const int* nodes = (const int*)d_in[15];
  float* out = (float*)d_out;

  int* active = (int*)d_ws;
  float* memb = (float*)((char*)d_ws + WS_MEMB);
  unsigned short* w1t = (unsigned short*)((char*)d_ws + WS_W1T);
  unsigned short* w3t = (unsigned short*)((char*)d_ws + WS_W3T);

  init_k<<<194, 256, 0, stream>>>(cidx, active, W1, w1t, W3, w3t);
  member_emb_k<<<KK, 128, 0, stream>>>(c2n, n2c, mscore, mnum, active, cidx,
                                       cemb, memb);
  main_k<<<NN / 16, 512, 0, stream>>>(node_emb, cemb, memb, w1t, b1, W2, b2,
                                      w3t, b3, W4, b4, n2c, active, nodes, out);
}

// Round 12
// 29.825 us; speedup vs baseline: 1.6442x; 1.3512x over previous
//
#include <hip/hip_runtime.h>

#define NN 20000
#define VV 100000
#define CC 5000
#define MM 32
#define KK 2048
#define DD 128

// ws: active[CC] @0 ; memb @32768 (2.56MB) ; w1f bf16 @2592768 (96KB) ; w3f bf16 @2691072 (16KB)
#define WS_MEMB 32768
#define WS_W1F  2592768
#define WS_W3F  2691072

typedef __attribute__((ext_vector_type(8))) short bf16x8;
typedef __attribute__((ext_vector_type(4))) float f32x4;

__device__ __forceinline__ unsigned f2bf_rne(float f) {  // bf16 in low 16 bits
  unsigned u = __builtin_bit_cast(unsigned, f);
  u += 0x7fffu + ((u >> 16) & 1u);
  return u >> 16;
}
__device__ __forceinline__ float bf2f(unsigned h) {
  unsigned u = h << 16;
  return __builtin_bit_cast(float, u);
}

// ---------------- K0: init = zero+scatter (block 0) | W1,W3 -> bf16 FRAGMENT order ------------
// Fragment order: elem (ct, ks, lane, e) at index ((ct*NKS+ks)*64+lane)*8+e holds
// B[k][col] with col = ct*16 + (lane&15), k = ks*32 + (lane>>4)*8 + e.
// MFMA B-load for col-tile ct, k-step ks is then frag[(ct*NKS+ks)*64 + lane] -> 1KB contiguous.
__global__ __launch_bounds__(256) void init_k(const int* __restrict__ cidx,
    int* __restrict__ active, const float* __restrict__ W1,
    unsigned short* __restrict__ w1f, const float* __restrict__ W3,
    unsigned short* __restrict__ w3f) {
  int b = blockIdx.x, tid = threadIdx.x;
  if (b == 0) {
    for (int i = tid; i < CC; i += 256) active[i] = 0;
    __syncthreads();
    for (int k = tid; k < KK; k += 256) active[cidx[k]] = 1;
  } else if (b <= 192) {
    int i = (b - 1) * 256 + tid;      // 0..49151 ; w1f: 8 ct x 12 ks
    int e = i & 7, slot = i >> 3;
    int lane = slot & 63, g = slot >> 6;   // g = ct*12 + ks
    int ks = g % 12, ct = g / 12;
    int c = ct * 16 + (lane & 15);
    int k = ks * 32 + (lane >> 4) * 8 + e;
    w1f[i] = (unsigned short)f2bf_rne(W1[(size_t)k * DD + c]);
  } else {                              // b == 193 ; w3f: 4 ct x 4 ks = 8192 elems
    for (int i = tid; i < 64 * DD; i += 256) {
      int e = i & 7, slot = i >> 3;
      int lane = slot & 63, g = slot >> 6;  // g = ct*4 + ks
      int ks = g & 3, ct = g >> 2;
      int h = ct * 16 + (lane & 15);
      int k = ks * 32 + (lane >> 4) * 8 + e;
      w3f[i] = (unsigned short)f2bf_rne(W3[(size_t)k * 64 + h]);
    }
  }
}

// ---------------- K1: member embedding, driven by cidx (2048 blocks) ----------------
__global__ __launch_bounds__(128) void member_emb_k(const int* __restrict__ c2n,
    const int* __restrict__ n2c, const float* __restrict__ mscore,
    const int* __restrict__ mnum, const int* __restrict__ active,
    const int* __restrict__ cidx, const float* __restrict__ cemb,
    float* __restrict__ memb) {
  int c = cidx[blockIdx.x];  // active by construction
  __shared__ float s_sc[MM];
  __shared__ int s_nc[MM];
  int t = threadIdx.x;  // 0..127 = d
  if (t < MM) {
    int mem = c2n[c * MM + t];
    int nc = n2c[mem];
    bool valid = (t < mnum[c]) && (active[nc] != 0);
    s_nc[t] = nc;
    s_sc[t] = valid ? mscore[c * MM + t] : 0.f;
  }
  __syncthreads();
  float acc = 0.f;
  #pragma unroll
  for (int m = 0; m < MM; ++m)
    acc = fmaf(s_sc[m], cemb[(size_t)s_nc[m] * DD + t], acc);
  memb[(size_t)c * DD + t] = acc;
}

// ---------------- K2: main = feat stage (frag order) + pred1/pred2 MFMA + select --------------
// 512 thr, 16 rows/block, 1250 blocks. LDS ~25 KB -> 4 blocks/CU (thread-capped).
// A staged in LDS in fragment order (conflict-free lane*16 ds_read_b128);
// B read from global w1f/w3f in fragment order (1KB contiguous per wave-load).
// Wave w = pred1 col-tile (cols w*16..+15); pred2 tile ct2=w&3 (only w<4 writes).
// C/D mapping (verified R6): out_row = (lane>>4)*4 + j, col = tile_base + (lane&15).
__global__ __launch_bounds__(512) void main_k(const float* __restrict__ node_emb,
    const float* __restrict__ cemb, const float* __restrict__ memb,
    const unsigned short* __restrict__ w1f, const float* __restrict__ b1,
    const float* __restrict__ W2, const float* __restrict__ b2v,
    const unsigned short* __restrict__ w3f, const float* __restrict__ b3,
    const float* __restrict__ W4, const float* __restrict__ b4v,
    const int* __restrict__ n2c, const int* __restrict__ active,
    const int* __restrict__ nodes, float* __restrict__ out) {
  __shared__ __align__(16) unsigned short s_hi[12 * 64 * 8];  // 12 KB, frag order
  __shared__ __align__(16) unsigned short s_lo[12 * 64 * 8];  // 12 KB
  __shared__ int s_v[16], s_cm[16], s_use[16];
  __shared__ float s_r1[16][8], s_r2[16][4];
  int tid = threadIdx.x;
  int n0 = blockIdx.x * 16;
  if (tid < 16) {
    int v = nodes[n0 + tid], cm = n2c[v];
    s_v[tid] = v; s_cm[tid] = cm; s_use[tid] = active[cm];
  }
  __syncthreads();
  {  // stage feat hi/lo into FRAGMENT order: 16 rows x 96 float4, 3 per thread
    #pragma unroll
    for (int it = 0; it < 3; ++it) {
      int i4 = it * 512 + tid;
      int row = i4 / 96, pos = i4 % 96;
      int off = pos * 4;                      // feat column base, off%8 in {0,4}
      int use = s_use[row];
      float4 f;
      if (off < DD) {
        f = *(const float4*)(node_emb + (size_t)(n0 + row) * DD + off);
      } else if (off < 2 * DD) {
        f = use ? *(const float4*)(cemb + (size_t)s_v[row] * DD + (off - DD))
                : make_float4(0.f, 0.f, 0.f, 0.f);
      } else {
        f = use ? *(const float4*)(memb + (size_t)s_cm[row] * DD + (off - 2 * DD))
                : make_float4(0.f, 0.f, 0.f, 0.f);
      }
      unsigned h0 = f2bf_rne(f.x), h1 = f2bf_rne(f.y),
               h2 = f2bf_rne(f.z), h3 = f2bf_rne(f.w);
      unsigned l0 = f2bf_rne(f.x - bf2f(h0)), l1 = f2bf_rne(f.y - bf2f(h1)),
               l2 = f2bf_rne(f.z - bf2f(h2)), l3 = f2bf_rne(f.w - bf2f(h3));
      // fragment index: ks = off>>5, lane_slot = row + 16*((off>>3)&3), e0 = off&7
      int base = (((off >> 5) * 64) + row + 16 * ((off >> 3) & 3)) * 8 + (off & 7);
      *(uint2*)&s_hi[base] = make_uint2(h0 | (h1 << 16), h2 | (h3 << 16));
      *(uint2*)&s_lo[base] = make_uint2(l0 | (l1 << 16), l2 | (l3 << 16));
    }
  }
  __syncthreads();
  int lane = tid & 63, w = tid >> 6;
  int lrow = lane & 15, lkq = lane >> 4;
  const bf16x8* ahf = (const bf16x8*)s_hi;
  const bf16x8* alf = (const bf16x8*)s_lo;
  const bf16x8* b1f = (const bf16x8*)w1f + (size_t)w * 12 * 64 + lane;
  const bf16x8* b3f = (const bf16x8*)w3f + (size_t)(w & 3) * 4 * 64 + lane;
  f32x4 acc0 = {0.f, 0.f, 0.f, 0.f};
  f32x4 p2   = {0.f, 0.f, 0.f, 0.f};
  #pragma unroll
  for (int ks = 0; ks < 4; ++ks) {  // pred1 + pred2 share A-frags (k < 128)
    bf16x8 vah = ahf[ks * 64 + lane];
    bf16x8 val = alf[ks * 64 + lane];
    bf16x8 vb0 = b1f[ks * 64];
    bf16x8 vb2 = b3f[ks * 64];
    acc0 = __builtin_amdgcn_mfma_f32_16x16x32_bf16(vah, vb0, acc0, 0, 0, 0);
    acc0 = __builtin_amdgcn_mfma_f32_16x16x32_bf16(val, vb0, acc0, 0, 0, 0);
    p2   = __builtin_amdgcn_mfma_f32_16x16x32_bf16(vah, vb2, p2, 0, 0, 0);
    p2   = __builtin_amdgcn_mfma_f32_16x16x32_bf16(val, vb2, p2, 0, 0, 0);
  }
  #pragma unroll
  for (int ks = 4; ks < 12; ++ks) {  // pred1 only
    bf16x8 vah = ahf[ks * 64 + lane];
    bf16x8 val = alf[ks * 64 + lane];
    bf16x8 vb0 = b1f[ks * 64];
    acc0 = __builtin_amdgcn_mfma_f32_16x16x32_bf16(vah, vb0, acc0, 0, 0, 0);
    acc0 = __builtin_amdgcn_mfma_f32_16x16x32_bf16(val, vb0, acc0, 0, 0, 0);
  }
  {  // pred1 epilogue: reduce 16 cols of tile w
    int c0 = w * 16 + lrow;
    float b1a = b1[c0], w2a = W2[c0];
    float vsum[4];
    #pragma unroll
    for (int j = 0; j < 4; ++j) vsum[j] = fmaxf(acc0[j] + b1a, 0.f) * w2a;
    #pragma unroll
    for (int m = 1; m <= 8; m <<= 1)
      #pragma unroll
      for (int j = 0; j < 4; ++j) vsum[j] += __shfl_xor(vsum[j], m, 64);
    if (lrow == 0) {
      #pragma unroll
      for (int j = 0; j < 4; ++j) s_r1[lkq * 4 + j][w] = vsum[j];
    }
  }
  {  // pred2 epilogue (waves 0-3 write)
    int h = (w & 3) * 16 + lrow;
    float b3v = b3[h], w4v = W4[h];
    float q[4];
    #pragma unroll
    for (int j = 0; j < 4; ++j) q[j] = fmaxf(p2[j] + b3v, 0.f) * w4v;
    #pragma unroll
    for (int m = 1; m <= 8; m <<= 1)
      #pragma unroll
      for (int j = 0; j < 4; ++j) q[j] += __shfl_xor(q[j], m, 64);
    if (lrow == 0 && w < 4) {
      #pragma unroll
      for (int j = 0; j < 4; ++j) s_r2[lkq * 4 + j][w] = q[j];
    }
  }
  __syncthreads();
  if (tid < 16) {
    float r;
    if (s_use[tid]) {
      r = b2v[0];
      #pragma unroll
      for (int c = 0; c < 8; ++c) r += s_r1[tid][c];
    } else {
      r = s_r2[tid][0] + s_r2[tid][1] + s_r2[tid][2] + s_r2[tid][3] + b4v[0];
    }
    out[n0 + tid] = r;
  }
}

extern "C" void kernel_launch(void* const* d_in, const int* in_sizes, int n_in,
                              void* d_out, int out_size, void* d_ws, size_t ws_size,
                              hipStream_t stream) {
  const float* node_emb = (const float*)d_in[0];
  const float* mscore   = (const float*)d_in[1];
  const float* cemb     = (const float*)d_in[2];
  const float* W1 = (const float*)d_in[3];
  const float* b1 = (const float*)d_in[4];
  const float* W2 = (const float*)d_in[5];
  const float* b2 = (const float*)d_in[6];
  const float* W3 = (const float*)d_in[7];
  const float* b3 = (const float*)d_in[8];
  const float* W4 = (const float*)d_in[9];
  const float* b4 = (const float*)d_in[10];
  const int* n2c   = (const int*)d_in[11];
  const int* c2n   = (const int*)d_in[12];
  const int* mnum  = (const int*)d_in[13];
  const int* cidx  = (const int*)d_in[14];
  const int* nodes = (const int*)d_in[15];
  float* out = (float*)d_out;

  int* active = (int*)d_ws;
  float* memb = (float*)((char*)d_ws + WS_MEMB);
  unsigned short* w1f = (unsigned short*)((char*)d_ws + WS_W1F);
  unsigned short* w3f = (unsigned short*)((char*)d_ws + WS_W3F);

  init_k<<<194, 256, 0, stream>>>(cidx, active, W1, w1f, W3, w3f);
  member_emb_k<<<KK, 128, 0, stream>>>(c2n, n2c, mscore, mnum, active, cidx,
                                       cemb, memb);
  main_k<<<NN / 16, 512, 0, stream>>>(node_emb, cemb, memb, w1f, b1, W2, b2,
                                      w3f, b3, W4, b4, n2c, active, nodes, out);
}

// Round 13
// 28.028 us; speedup vs baseline: 1.7496x; 1.0641x over previous
//
#include <hip/hip_runtime.h>

#define NN 20000
#define VV 100000
#define CC 5000
#define MM 32
#define KK 2048
#define DD 128

// ws: active[CC] @0 ; memb @32768 (2.56MB) ; w1f bf16 @2592768 (96KB) ; w3f bf16 @2691072 (16KB)
#define WS_MEMB 32768
#define WS_W1F  2592768
#define WS_W3F  2691072

typedef __attribute__((ext_vector_type(8))) short bf16x8;
typedef __attribute__((ext_vector_type(4))) float f32x4;

__device__ __forceinline__ unsigned f2bf_rne(float f) {  // bf16 in low 16 bits
  unsigned u = __builtin_bit_cast(unsigned, f);
  u += 0x7fffu + ((u >> 16) & 1u);
  return u >> 16;
}

// ---------------- K0: init = zero+scatter (block 0) | W1,W3 -> bf16 FRAGMENT order ------------
// Fragment order: elem (ct, ks, lane, e) at index ((ct*NKS+ks)*64+lane)*8+e holds
// B[k][col] with col = ct*16 + (lane&15), k = ks*32 + (lane>>4)*8 + e.
__global__ __launch_bounds__(256) void init_k(const int* __restrict__ cidx,
    int* __restrict__ active, const float* __restrict__ W1,
    unsigned short* __restrict__ w1f, const float* __restrict__ W3,
    unsigned short* __restrict__ w3f) {
  int b = blockIdx.x, tid = threadIdx.x;
  if (b == 0) {
    for (int i = tid; i < CC; i += 256) active[i] = 0;
    __syncthreads();
    for (int k = tid; k < KK; k += 256) active[cidx[k]] = 1;
  } else if (b <= 192) {
    int i = (b - 1) * 256 + tid;      // 0..49151 ; w1f: 8 ct x 12 ks
    int e = i & 7, slot = i >> 3;
    int lane = slot & 63, g = slot >> 6;   // g = ct*12 + ks
    int ks = g % 12, ct = g / 12;
    int c = ct * 16 + (lane & 15);
    int k = ks * 32 + (lane >> 4) * 8 + e;
    w1f[i] = (unsigned short)f2bf_rne(W1[(size_t)k * DD + c]);
  } else {                              // b == 193 ; w3f: 4 ct x 4 ks = 8192 elems
    for (int i = tid; i < 64 * DD; i += 256) {
      int e = i & 7, slot = i >> 3;
      int lane = slot & 63, g = slot >> 6;  // g = ct*4 + ks
      int ks = g & 3, ct = g >> 2;
      int h = ct * 16 + (lane & 15);
      int k = ks * 32 + (lane >> 4) * 8 + e;
      w3f[i] = (unsigned short)f2bf_rne(W3[(size_t)k * 64 + h]);
    }
  }
}

// ---------------- K1: member embedding, driven by cidx (2048 blocks) ----------------
__global__ __launch_bounds__(128) void member_emb_k(const int* __restrict__ c2n,
    const int* __restrict__ n2c, const float* __restrict__ mscore,
    const int* __restrict__ mnum, const int* __restrict__ active,
    const int* __restrict__ cidx, const float* __restrict__ cemb,
    float* __restrict__ memb) {
  int c = cidx[blockIdx.x];  // active by construction
  __shared__ float s_sc[MM];
  __shared__ int s_nc[MM];
  int t = threadIdx.x;  // 0..127 = d
  if (t < MM) {
    int mem = c2n[c * MM + t];
    int nc = n2c[mem];
    bool valid = (t < mnum[c]) && (active[nc] != 0);
    s_nc[t] = nc;
    s_sc[t] = valid ? mscore[c * MM + t] : 0.f;
  }
  __syncthreads();
  float acc = 0.f;
  #pragma unroll
  for (int m = 0; m < MM; ++m)
    acc = fmaf(s_sc[m], cemb[(size_t)s_nc[m] * DD + t], acc);
  memb[(size_t)c * DD + t] = acc;
}

// ---------------- K2: main = feat stage (frag order, single bf16) + MFMA + select -------------
// 512 thr, 16 rows/block, 1250 blocks. LDS ~13 KB.
// A staged in LDS in fragment order (conflict-free lane*16 ds_read_b128);
// B read from global w1f/w3f in fragment order (1KB contiguous per wave-load).
// Wave w = pred1 col-tile (cols w*16..+15); pred2 tile w&3 (only w<4 writes).
// C/D mapping (verified R6): out_row = (lane>>4)*4 + j, col = tile_base + (lane&15).
__global__ __launch_bounds__(512) void main_k(const float* __restrict__ node_emb,
    const float* __restrict__ cemb, const float* __restrict__ memb,
    const unsigned short* __restrict__ w1f, const float* __restrict__ b1,
    const float* __restrict__ W2, const float* __restrict__ b2v,
    const unsigned short* __restrict__ w3f, const float* __restrict__ b3,
    const float* __restrict__ W4, const float* __restrict__ b4v,
    const int* __restrict__ n2c, const int* __restrict__ active,
    const int* __restrict__ nodes, float* __restrict__ out) {
  __shared__ __align__(16) unsigned short s_hi[12 * 64 * 8];  // 12 KB, frag order
  __shared__ int s_v[16], s_cm[16], s_use[16];
  __shared__ float s_r1[16][8], s_r2[16][4];
  int tid = threadIdx.x;
  int n0 = blockIdx.x * 16;
  if (tid < 16) {
    int v = nodes[n0 + tid], cm = n2c[v];
    s_v[tid] = v; s_cm[tid] = cm; s_use[tid] = active[cm];
  }
  __syncthreads();
  {  // stage feat bf16 into FRAGMENT order: 16 rows x 96 float4, 3 per thread
    #pragma unroll
    for (int it = 0; it < 3; ++it) {
      int i4 = it * 512 + tid;
      int row = i4 / 96, pos = i4 % 96;
      int off = pos * 4;                      // feat column base, off%8 in {0,4}
      int use = s_use[row];
      float4 f;
      if (off < DD) {
        f = *(const float4*)(node_emb + (size_t)(n0 + row) * DD + off);
      } else if (off < 2 * DD) {
        f = use ? *(const float4*)(cemb + (size_t)s_v[row] * DD + (off - DD))
                : make_float4(0.f, 0.f, 0.f, 0.f);
      } else {
        f = use ? *(const float4*)(memb + (size_t)s_cm[row] * DD + (off - 2 * DD))
                : make_float4(0.f, 0.f, 0.f, 0.f);
      }
      unsigned h0 = f2bf_rne(f.x), h1 = f2bf_rne(f.y),
               h2 = f2bf_rne(f.z), h3 = f2bf_rne(f.w);
      // fragment index: ks = off>>5, lane_slot = row + 16*((off>>3)&3), e0 = off&7
      int base = (((off >> 5) * 64) + row + 16 * ((off >> 3) & 3)) * 8 + (off & 7);
      *(uint2*)&s_hi[base] = make_uint2(h0 | (h1 << 16), h2 | (h3 << 16));
    }
  }
  __syncthreads();
  int lane = tid & 63, w = tid >> 6;
  int lrow = lane & 15, lkq = lane >> 4;
  const bf16x8* ahf = (const bf16x8*)s_hi;
  const bf16x8* b1f = (const bf16x8*)w1f + (size_t)w * 12 * 64 + lane;
  const bf16x8* b3f = (const bf16x8*)w3f + (size_t)(w & 3) * 4 * 64 + lane;
  f32x4 acc0 = {0.f, 0.f, 0.f, 0.f};
  f32x4 p2   = {0.f, 0.f, 0.f, 0.f};
  #pragma unroll
  for (int ks = 0; ks < 4; ++ks) {  // pred1 + pred2 share A-frags (k < 128)
    bf16x8 vah = ahf[ks * 64 + lane];
    bf16x8 vb0 = b1f[ks * 64];
    bf16x8 vb2 = b3f[ks * 64];
    acc0 = __builtin_amdgcn_mfma_f32_16x16x32_bf16(vah, vb0, acc0, 0, 0, 0);
    p2   = __builtin_amdgcn_mfma_f32_16x16x32_bf16(vah, vb2, p2, 0, 0, 0);
  }
  #pragma unroll
  for (int ks = 4; ks < 12; ++ks) {  // pred1 only
    bf16x8 vah = ahf[ks * 64 + lane];
    bf16x8 vb0 = b1f[ks * 64];
    acc0 = __builtin_amdgcn_mfma_f32_16x16x32_bf16(vah, vb0, acc0, 0, 0, 0);
  }
  {  // pred1 epilogue: reduce 16 cols of tile w
    int c0 = w * 16 + lrow;
    float b1a = b1[c0], w2a = W2[c0];
    float vsum[4];
    #pragma unroll
    for (int j = 0; j < 4; ++j) vsum[j] = fmaxf(acc0[j] + b1a, 0.f) * w2a;
    #pragma unroll
    for (int m = 1; m <= 8; m <<= 1)
      #pragma unroll
      for (int j = 0; j < 4; ++j) vsum[j] += __shfl_xor(vsum[j], m, 64);
    if (lrow == 0) {
      #pragma unroll
      for (int j = 0; j < 4; ++j) s_r1[lkq * 4 + j][w] = vsum[j];
    }
  }
  {  // pred2 epilogue (waves 0-3 write)
    int h = (w & 3) * 16 + lrow;
    float b3v = b3[h], w4v = W4[h];
    float q[4];
    #pragma unroll
    for (int j = 0; j < 4; ++j) q[j] = fmaxf(p2[j] + b3v, 0.f) * w4v;
    #pragma unroll
    for (int m = 1; m <= 8; m <<= 1)
      #pragma unroll
      for (int j = 0; j < 4; ++j) q[j] += __shfl_xor(q[j], m, 64);
    if (lrow == 0 && w < 4) {
      #pragma unroll
      for (int j = 0; j < 4; ++j) s_r2[lkq * 4 + j][w] = q[j];
    }
  }
  __syncthreads();
  if (tid < 16) {
    float r;
    if (s_use[tid]) {
      r = b2v[0];
      #pragma unroll
      for (int c = 0; c < 8; ++c) r += s_r1[tid][c];
    } else {
      r = s_r2[tid][0] + s_r2[tid][1] + s_r2[tid][2] + s_r2[tid][3] + b4v[0];
    }
    out[n0 + tid] = r;
  }
}

extern "C" void kernel_launch(void* const* d_in, const int* in_sizes, int n_in,
                              void* d_out, int out_size, void* d_ws, size_t ws_size,
                              hipStream_t stream) {
  const float* node_emb = (const float*)d_in[0];
  const float* mscore   = (const float*)d_in[1];
  const float* cemb     = (const float*)d_in[2];
  const float* W1 = (const float*)d_in[3];
  const float* b1 = (const float*)d_in[4];
  const float* W2 = (const float*)d_in[5];
  const float* b2 = (const float*)d_in[6];
  const float* W3 = (const float*)d_in[7];
  const float* b3 = (const float*)d_in[8];
  const float* W4 = (const float*)d_in[9];
  const float* b4 = (const float*)d_in[10];
  const int* n2c   = (const int*)d_in[11];
  const int* c2n   = (const int*)d_in[12];
  const int* mnum  = (const int*)d_in[13];
  const int* cidx  = (const int*)d_in[14];
  const int* nodes = (const int*)d_in[15];
  float* out = (float*)d_out;

  int* active = (int*)d_ws;
  float* memb = (float*)((char*)d_ws + WS_MEMB);
  unsigned short* w1f = (unsigned short*)((char*)d_ws + WS_W1F);
  unsigned short* w3f = (unsigned short*)((char*)d_ws + WS_W3F);

  init_k<<<194, 256, 0, stream>>>(cidx, active, W1, w1f, W3, w3f);
  member_emb_k<<<KK, 128, 0, stream>>>(c2n, n2c, mscore, mnum, active, cidx,
                                       cemb, memb);
  main_k<<<NN / 16, 512, 0, stream>>>(node_emb, cemb, memb, w1f, b1, W2, b2,
                                      w3f, b3, W4, b4, n2c, active, nodes, out);
}